// Round 1
// baseline (953.512 us; speedup 1.0000x reference)
//
#include <hip/hip_runtime.h>

// Problem constants (fixed by the reference)
#define THREADS 256
#define ROWS    32          // rows (masked nodes) per block
#define INDIM   208         // 16 + 3*64
#define H1DIM   128
#define H2DIM   64
#define KT      16          // K-slice for W1 staging
#define NT1     (INDIM/KT)  // 13
#define ATS     36          // padded LDS stride for A-tile (mult of 4, breaks bank pattern)
#define H1S     132         // padded stride for h1 tile [32][132]

__global__ __launch_bounds__(THREADS, 2)
void stage_policy_mlp(const float* __restrict__ x,
                      const float* __restrict__ h_node,
                      const float* __restrict__ h_dag,
                      const float* __restrict__ h_glob,
                      const float* __restrict__ W1,
                      const float* __restrict__ b1,
                      const float* __restrict__ W2,
                      const float* __restrict__ b2,
                      const float* __restrict__ W3,
                      const float* __restrict__ b3,
                      const int*   __restrict__ stage_idx,
                      const int*   __restrict__ batch,
                      const int*   __restrict__ nsa,
                      float*       __restrict__ out,
                      int M)
{
    // LDS: A-tile (transposed, [INDIM][ATS]) reused as h1 tile ([ROWS][H1S]);
    //      W region: W1 double-buffer (2x2048 floats) reused as full W2 (8192 floats)
    __shared__ float At_s[INDIM * ATS];     // 29,952 B
    __shared__ float Wreg[KT * H1DIM * 2 > H1DIM * H2DIM ? KT * H1DIM * 2 : H1DIM * H2DIM]; // 8192 floats = 32 KB
    __shared__ int rIdx[ROWS];
    __shared__ int rBm[ROWS];
    __shared__ int rG[ROWS];

    const int tid = threadIdx.x;
    const int m0  = blockIdx.x * ROWS;
    const int tr  = tid >> 5;    // 0..7  -> row base 4*tr
    const int tc  = tid & 31;    // 0..31 -> col base 4*tc (L1) / 2*tc (L2)

    // ---- per-row metadata: gather index, dag id, graph id ----
    if (tid < ROWS) {
        int m   = m0 + tid;
        int idx = stage_idx[m];
        rIdx[tid] = idx;
        rBm[tid]  = batch[idx];
        int g = 0, cum = 0;
        #pragma unroll
        for (int i = 0; i < 16; ++i) { cum += nsa[i]; if (m >= cum) g = i + 1; }
        rG[tid] = g;
    }
    __syncthreads();

    // ---- stage A-tile transposed: At[k][r] ----
    // x: 16 floats/row -> 128 float4 units
    if (tid < 128) {
        int r = tid >> 2, q = tid & 3;
        float4 v = *(const float4*)(x + (size_t)rIdx[r] * 16 + q * 4);
        int k = q * 4;
        At_s[(k + 0) * ATS + r] = v.x;
        At_s[(k + 1) * ATS + r] = v.y;
        At_s[(k + 2) * ATS + r] = v.z;
        At_s[(k + 3) * ATS + r] = v.w;
    }
    // h_node: 64 floats/row -> 512 units
    for (int u = tid; u < 512; u += THREADS) {
        int r = u >> 4, q = u & 15;
        float4 v = *(const float4*)(h_node + (size_t)rIdx[r] * 64 + q * 4);
        int k = 16 + q * 4;
        At_s[(k + 0) * ATS + r] = v.x;
        At_s[(k + 1) * ATS + r] = v.y;
        At_s[(k + 2) * ATS + r] = v.z;
        At_s[(k + 3) * ATS + r] = v.w;
    }
    // h_dag[batch_m]
    for (int u = tid; u < 512; u += THREADS) {
        int r = u >> 4, q = u & 15;
        float4 v = *(const float4*)(h_dag + (size_t)rBm[r] * 64 + q * 4);
        int k = 80 + q * 4;
        At_s[(k + 0) * ATS + r] = v.x;
        At_s[(k + 1) * ATS + r] = v.y;
        At_s[(k + 2) * ATS + r] = v.z;
        At_s[(k + 3) * ATS + r] = v.w;
    }
    // h_glob[g]
    for (int u = tid; u < 512; u += THREADS) {
        int r = u >> 4, q = u & 15;
        float4 v = *(const float4*)(h_glob + (size_t)rG[r] * 64 + q * 4);
        int k = 144 + q * 4;
        At_s[(k + 0) * ATS + r] = v.x;
        At_s[(k + 1) * ATS + r] = v.y;
        At_s[(k + 2) * ATS + r] = v.z;
        At_s[(k + 3) * ATS + r] = v.w;
    }

    // ---- W1 K-slice staging (reg double-buffer): slice t = W1[t*16..+16)[0..128) = 2048 floats ----
    float4 wst0, wst1;
    {   // preload tile 0, write, preload tile 1
        wst0 = *(const float4*)(W1 + 0 * KT * H1DIM + tid * 4);
        wst1 = *(const float4*)(W1 + 0 * KT * H1DIM + (tid + 256) * 4);
        *(float4*)(Wreg + 0 * KT * H1DIM + tid * 4)         = wst0;
        *(float4*)(Wreg + 0 * KT * H1DIM + (tid + 256) * 4) = wst1;
        wst0 = *(const float4*)(W1 + 1 * KT * H1DIM + tid * 4);
        wst1 = *(const float4*)(W1 + 1 * KT * H1DIM + (tid + 256) * 4);
    }
    __syncthreads();   // A-tile + W1 slice 0 visible

    // ---- layer 1: [32x208] @ [208x128], 4x4 micro-tile/thread ----
    float acc1[4][4];
    #pragma unroll
    for (int i = 0; i < 4; ++i)
        #pragma unroll
        for (int j = 0; j < 4; ++j) acc1[i][j] = 0.f;

    for (int t = 0; t < NT1; ++t) {
        const int cur = t & 1;
        if (t + 1 < NT1) {  // write next slice (already in regs) to other buffer
            *(float4*)(Wreg + (1 ^ cur) * KT * H1DIM + tid * 4)         = wst0;
            *(float4*)(Wreg + (1 ^ cur) * KT * H1DIM + (tid + 256) * 4) = wst1;
        }
        if (t + 2 < NT1) {  // prefetch slice t+2
            wst0 = *(const float4*)(W1 + (t + 2) * KT * H1DIM + tid * 4);
            wst1 = *(const float4*)(W1 + (t + 2) * KT * H1DIM + (tid + 256) * 4);
        }
        const float* Wb = Wreg + cur * KT * H1DIM;
        #pragma unroll
        for (int kk = 0; kk < KT; ++kk) {
            const int k = t * KT + kk;
            float av[4], bv[4];
            *(float4*)av = *(const float4*)(At_s + k * ATS + 4 * tr);
            *(float4*)bv = *(const float4*)(Wb + kk * H1DIM + 4 * tc);
            #pragma unroll
            for (int i = 0; i < 4; ++i)
                #pragma unroll
                for (int j = 0; j < 4; ++j)
                    acc1[i][j] += av[i] * bv[j];
        }
        __syncthreads();   // slice reads done; next-buffer writes visible
    }

    // ---- epilogue L1: bias + relu -> h1 in LDS (reuse A-tile region) ----
    float* h1s = At_s;  // [ROWS][H1S]
    {
        float4 bb1 = *(const float4*)(b1 + 4 * tc);
        #pragma unroll
        for (int i = 0; i < 4; ++i) {
            float4 v;
            v.x = fmaxf(acc1[i][0] + bb1.x, 0.f);
            v.y = fmaxf(acc1[i][1] + bb1.y, 0.f);
            v.z = fmaxf(acc1[i][2] + bb1.z, 0.f);
            v.w = fmaxf(acc1[i][3] + bb1.w, 0.f);
            *(float4*)(h1s + (4 * tr + i) * H1S + 4 * tc) = v;
        }
    }
    // stage full W2 into Wreg (8192 floats), 8 float4/thread
    #pragma unroll
    for (int u = 0; u < 8; ++u) {
        int o = (u * THREADS + tid) * 4;
        *(float4*)(Wreg + o) = *(const float4*)(W2 + o);
    }
    __syncthreads();

    // ---- layer 2: [32x128] @ [128x64], 4x2 micro-tile/thread ----
    float acc2[4][2];
    #pragma unroll
    for (int i = 0; i < 4; ++i) { acc2[i][0] = 0.f; acc2[i][1] = 0.f; }

    for (int k = 0; k < H1DIM; k += 4) {
        float av4[4][4];
        #pragma unroll
        for (int i = 0; i < 4; ++i)
            *(float4*)av4[i] = *(const float4*)(h1s + (4 * tr + i) * H1S + k);
        #pragma unroll
        for (int j = 0; j < 4; ++j) {
            float2 b = *(const float2*)(Wreg + (k + j) * H2DIM + 2 * tc);
            #pragma unroll
            for (int i = 0; i < 4; ++i) {
                acc2[i][0] += av4[i][j] * b.x;
                acc2[i][1] += av4[i][j] * b.y;
            }
        }
    }

    // ---- layer 3: bias+relu, dot with W3, 32-lane reduce, store ----
    {
        float2 bb2 = *(const float2*)(b2 + 2 * tc);
        float2 w3  = *(const float2*)(W3 + 2 * tc);
        float part[4];
        #pragma unroll
        for (int i = 0; i < 4; ++i) {
            float p0 = fmaxf(acc2[i][0] + bb2.x, 0.f);
            float p1 = fmaxf(acc2[i][1] + bb2.y, 0.f);
            part[i] = p0 * w3.x + p1 * w3.y;
        }
        #pragma unroll
        for (int s = 16; s >= 1; s >>= 1) {
            #pragma unroll
            for (int i = 0; i < 4; ++i) part[i] += __shfl_xor(part[i], s);
        }
        if (tc == 0) {
            float bias3 = b3[0];
            float4 o;
            o.x = part[0] + bias3;
            o.y = part[1] + bias3;
            o.z = part[2] + bias3;
            o.w = part[3] + bias3;
            *(float4*)(out + m0 + 4 * tr) = o;
        }
    }
}

extern "C" void kernel_launch(void* const* d_in, const int* in_sizes, int n_in,
                              void* d_out, int out_size, void* d_ws, size_t ws_size,
                              hipStream_t stream) {
    const float* x       = (const float*)d_in[0];
    const float* h_node  = (const float*)d_in[1];
    const float* h_dag   = (const float*)d_in[2];
    const float* h_glob  = (const float*)d_in[3];
    const float* W1      = (const float*)d_in[4];
    const float* b1      = (const float*)d_in[5];
    const float* W2      = (const float*)d_in[6];
    const float* b2      = (const float*)d_in[7];
    const float* W3      = (const float*)d_in[8];
    const float* b3      = (const float*)d_in[9];
    const int* stage_idx = (const int*)d_in[10];
    const int* batch     = (const int*)d_in[11];
    const int* nsa       = (const int*)d_in[12];
    float* out           = (float*)d_out;

    const int M = in_sizes[10];          // 500,000
    const int grid = (M + ROWS - 1) / ROWS;   // 15,625

    hipLaunchKernelGGL(stage_policy_mlp, dim3(grid), dim3(THREADS), 0, stream,
                       x, h_node, h_dag, h_glob, W1, b1, W2, b2, W3, b3,
                       stage_idx, batch, nsa, out, M);
}

// Round 2
// 498.940 us; speedup vs baseline: 1.9111x; 1.9111x over previous
//
#include <hip/hip_runtime.h>
#include <hip/hip_bf16.h>

#define THREADS 256
#define ROWS    64          // rows per block
#define INDIM   208         // 16 + 3*64
#define KPAD    224         // 7 * 32 (MFMA K-steps)
#define H1DIM   128
#define H2DIM   64
#define AS      232         // A-tile LDS stride (bf16): 16B-aligned, 2-way banks (free)
#define H1S     136         // h1 LDS stride (bf16): 16B-aligned, 2-way banks (free)

typedef __attribute__((ext_vector_type(8))) short short8;   // 8 bf16 = 4 VGPRs (guide-verified frag type)
typedef __attribute__((ext_vector_type(4))) float f32x4;    // MFMA accumulator

static __device__ __forceinline__ short f2bf(float f) {
    return __builtin_bit_cast(short, __float2bfloat16(f));  // RNE; compiler packs to v_cvt_pk_bf16_f32
}

// load 8 fp32, convert, store 16B to LDS
static __device__ __forceinline__ void stage8(short* dst, const float* src) {
    float4 a = *(const float4*)src;
    float4 b = *(const float4*)(src + 4);
    short8 v;
    v[0] = f2bf(a.x); v[1] = f2bf(a.y); v[2] = f2bf(a.z); v[3] = f2bf(a.w);
    v[4] = f2bf(b.x); v[5] = f2bf(b.y); v[6] = f2bf(b.z); v[7] = f2bf(b.w);
    *(short8*)dst = v;
}

// ---- prep: convert+transpose weights into d_ws (re-run every call; ws is re-poisoned) ----
// w1t: [128 cols][224 k] bf16 (k>=208 zero)   w2t: [64 cols][128 k] bf16
__global__ void prep_weights(const float* __restrict__ W1f, const float* __restrict__ W2f,
                             short* __restrict__ w1t, short* __restrict__ w2t) {
    int i = blockIdx.x * blockDim.x + threadIdx.x;
    if (i < H1DIM * KPAD) {
        int c = i / KPAD, k = i % KPAD;
        w1t[i] = f2bf(k < INDIM ? W1f[k * H1DIM + c] : 0.f);
    } else {
        int t = i - H1DIM * KPAD;
        if (t < H2DIM * H1DIM) {
            int c = t / H1DIM, k = t % H1DIM;
            w2t[t] = f2bf(W2f[k * H2DIM + c]);
        }
    }
}

__global__ __launch_bounds__(THREADS, 2)
void stage_policy_mlp(const float* __restrict__ x,
                      const float* __restrict__ h_node,
                      const float* __restrict__ h_dag,
                      const float* __restrict__ h_glob,
                      const float* __restrict__ b1,
                      const float* __restrict__ b2,
                      const float* __restrict__ W3,
                      const float* __restrict__ b3,
                      const int*   __restrict__ stage_idx,
                      const int*   __restrict__ batch,
                      const int*   __restrict__ nsa,
                      const short* __restrict__ w1t,
                      const short* __restrict__ w2t,
                      float*       __restrict__ out,
                      int M)
{
    __shared__ short Asm[ROWS * AS];            // 29,696 B; reused as h1 [64][H1S] (17,408 B)
    __shared__ int rIdx[ROWS], rBm[ROWS], rG[ROWS];

    const int tid  = threadIdx.x;
    const int lane = tid & 63;
    const int w    = tid >> 6;       // wave 0..3
    const int l15  = lane & 15;
    const int lh   = lane >> 4;      // 0..3
    const int m0   = blockIdx.x * ROWS;
    const int wr   = w & 1;          // row half: rows 32*wr .. +31
    const int wc   = w >> 1;         // col half: cols 64*wc .. +63

    // ---- B-fragment preload for layer 1 (L2-resident ws; in flight during staging) ----
    short8 bw1[4][7];
    #pragma unroll
    for (int j = 0; j < 4; ++j)
        #pragma unroll
        for (int k = 0; k < 7; ++k)
            bw1[j][k] = *(const short8*)(w1t + ((wc * 4 + j) * 16 + l15) * KPAD + k * 32 + lh * 8);

    // ---- per-row metadata ----
    if (tid < ROWS) {
        int m = m0 + tid; if (m >= M) m = M - 1;
        int idx = stage_idx[m];
        rIdx[tid] = idx;
        rBm[tid]  = batch[idx];
        int g = 0, cum = 0;
        #pragma unroll
        for (int i = 0; i < 16; ++i) { cum += nsa[i]; if (m >= cum) g = i + 1; }
        rG[tid] = g > 15 ? 15 : g;
    }
    __syncthreads();

    // ---- gather A-tile as bf16 [64 rows][AS], k-major ----
    if (tid < 128) {                                   // x: 16 f/row
        int r = tid >> 1, q = tid & 1;
        stage8(&Asm[r * AS + q * 8], x + (size_t)rIdx[r] * 16 + q * 8);
    }
    for (int u = tid; u < 512; u += THREADS) {         // h_node
        int r = u >> 3, q = u & 7;
        stage8(&Asm[r * AS + 16 + q * 8], h_node + (size_t)rIdx[r] * 64 + q * 8);
    }
    for (int u = tid; u < 512; u += THREADS) {         // h_dag[batch]
        int r = u >> 3, q = u & 7;
        stage8(&Asm[r * AS + 80 + q * 8], h_dag + (size_t)rBm[r] * 64 + q * 8);
    }
    for (int u = tid; u < 512; u += THREADS) {         // h_glob[g]
        int r = u >> 3, q = u & 7;
        stage8(&Asm[r * AS + 144 + q * 8], h_glob + (size_t)rG[r] * 64 + q * 8);
    }
    if (tid < 128) {                                   // zero pad k 208..223
        int r = tid >> 1, q = tid & 1;
        short8 z = {0,0,0,0,0,0,0,0};
        *(short8*)&Asm[r * AS + 208 + q * 8] = z;
    }
    __syncthreads();

    // ---- layer 1: [64x224] @ [224x128]; wave = 2 row-tiles x 4 col-tiles ----
    f32x4 acc1[2][4];
    #pragma unroll
    for (int i = 0; i < 2; ++i)
        #pragma unroll
        for (int j = 0; j < 4; ++j) { f32x4 z = {0.f,0.f,0.f,0.f}; acc1[i][j] = z; }

    #pragma unroll
    for (int k = 0; k < 7; ++k) {
        short8 a0 = *(const short8*)&Asm[(wr * 32      + l15) * AS + k * 32 + lh * 8];
        short8 a1 = *(const short8*)&Asm[(wr * 32 + 16 + l15) * AS + k * 32 + lh * 8];
        #pragma unroll
        for (int j = 0; j < 4; ++j) {
            acc1[0][j] = __builtin_amdgcn_mfma_f32_16x16x32_bf16(a0, bw1[j][k], acc1[0][j], 0, 0, 0);
            acc1[1][j] = __builtin_amdgcn_mfma_f32_16x16x32_bf16(a1, bw1[j][k], acc1[1][j], 0, 0, 0);
        }
    }
    __syncthreads();   // all A-tile reads done before overwriting region with h1

    // ---- epilogue L1: bias + relu -> bf16 h1 [64][H1S] (C-layout: col=l15, row=4*lh+p) ----
    short* h1s = Asm;
    #pragma unroll
    for (int i = 0; i < 2; ++i)
        #pragma unroll
        for (int j = 0; j < 4; ++j) {
            int c = (wc * 4 + j) * 16 + l15;
            float bias = b1[c];
            #pragma unroll
            for (int p = 0; p < 4; ++p) {
                int row = wr * 32 + i * 16 + lh * 4 + p;
                h1s[row * H1S + c] = f2bf(fmaxf(acc1[i][j][p] + bias, 0.f));
            }
        }

    // ---- W2 fragment preload (latency hidden by barrier) ----
    short8 bw2[4][4];
    #pragma unroll
    for (int j = 0; j < 4; ++j)
        #pragma unroll
        for (int k = 0; k < 4; ++k)
            bw2[j][k] = *(const short8*)(w2t + (j * 16 + l15) * H1DIM + k * 32 + lh * 8);
    __syncthreads();

    // ---- layer 2: [64x128] @ [128x64]; wave = 1 row-tile (rows 16w..) x 4 col-tiles ----
    f32x4 acc2[4];
    #pragma unroll
    for (int j = 0; j < 4; ++j) { f32x4 z = {0.f,0.f,0.f,0.f}; acc2[j] = z; }
    #pragma unroll
    for (int k = 0; k < 4; ++k) {
        short8 a2 = *(const short8*)&h1s[(w * 16 + l15) * H1S + k * 32 + lh * 8];
        #pragma unroll
        for (int j = 0; j < 4; ++j)
            acc2[j] = __builtin_amdgcn_mfma_f32_16x16x32_bf16(a2, bw2[j][k], acc2[j], 0, 0, 0);
    }

    // ---- layer 3: relu(h2)·W3, reduce over 64 cols (4 tiles in-lane + 16-lane shfl) ----
    float part[4] = {0.f, 0.f, 0.f, 0.f};
    #pragma unroll
    for (int j = 0; j < 4; ++j) {
        int c = j * 16 + l15;
        float bb = b2[c], w3 = W3[c];
        #pragma unroll
        for (int p = 0; p < 4; ++p)
            part[p] += fmaxf(acc2[j][p] + bb, 0.f) * w3;
    }
    #pragma unroll
    for (int s = 8; s >= 1; s >>= 1) {
        #pragma unroll
        for (int p = 0; p < 4; ++p) part[p] += __shfl_xor(part[p], s);
    }
    if (l15 == 0) {
        float bias3 = b3[0];
        #pragma unroll
        for (int p = 0; p < 4; ++p) {
            int m = m0 + w * 16 + lh * 4 + p;
            if (m < M) out[m] = part[p] + bias3;
        }
    }
}

extern "C" void kernel_launch(void* const* d_in, const int* in_sizes, int n_in,
                              void* d_out, int out_size, void* d_ws, size_t ws_size,
                              hipStream_t stream) {
    const float* x       = (const float*)d_in[0];
    const float* h_node  = (const float*)d_in[1];
    const float* h_dag   = (const float*)d_in[2];
    const float* h_glob  = (const float*)d_in[3];
    const float* W1      = (const float*)d_in[4];
    const float* b1      = (const float*)d_in[5];
    const float* W2      = (const float*)d_in[6];
    const float* b2      = (const float*)d_in[7];
    const float* W3      = (const float*)d_in[8];
    const float* b3      = (const float*)d_in[9];
    const int* stage_idx = (const int*)d_in[10];
    const int* batch     = (const int*)d_in[11];
    const int* nsa       = (const int*)d_in[12];
    float* out           = (float*)d_out;

    const int M = in_sizes[10];

    short* w1t = (short*)d_ws;                    // 128*224 bf16 = 57,344 B
    short* w2t = w1t + H1DIM * KPAD;              // 64*128  bf16 = 16,384 B

    const int prep_elems = H1DIM * KPAD + H2DIM * H1DIM;   // 36,864
    hipLaunchKernelGGL(prep_weights, dim3((prep_elems + THREADS - 1) / THREADS),
                       dim3(THREADS), 0, stream, W1, W2, w1t, w2t);

    const int grid = (M + ROWS - 1) / ROWS;
    hipLaunchKernelGGL(stage_policy_mlp, dim3(grid), dim3(THREADS), 0, stream,
                       x, h_node, h_dag, h_glob, b1, b2, W3, b3,
                       stage_idx, batch, nsa, w1t, w2t, out, M);
}

// Round 3
// 479.175 us; speedup vs baseline: 1.9899x; 1.0412x over previous
//
#include <hip/hip_runtime.h>
#include <hip/hip_bf16.h>

#define THREADS 256
#define ROWS    64          // rows per block
#define INDIM   208         // 16 + 3*64
#define KPAD    224         // 7 * 32 (MFMA K-steps)
#define H1DIM   128
#define H2DIM   64
#define AS      232         // A-tile LDS stride (bf16): 16B-aligned, 2-way banks (free)
#define H1S     136         // h1 LDS stride (bf16): 16B-aligned, 2-way banks (free)

typedef __attribute__((ext_vector_type(8))) short short8;   // 8 bf16 = 4 VGPRs
typedef __attribute__((ext_vector_type(4))) float f32x4;    // MFMA accumulator

static __device__ __forceinline__ short f2bf(float f) {
    return __builtin_bit_cast(short, __float2bfloat16(f));  // RNE
}

// load 8 fp32, convert, store 16B to LDS
static __device__ __forceinline__ void stage8(short* dst, const float* src) {
    float4 a = *(const float4*)src;
    float4 b = *(const float4*)(src + 4);
    short8 v;
    v[0] = f2bf(a.x); v[1] = f2bf(a.y); v[2] = f2bf(a.z); v[3] = f2bf(a.w);
    v[4] = f2bf(b.x); v[5] = f2bf(b.y); v[6] = f2bf(b.z); v[7] = f2bf(b.w);
    *(short8*)dst = v;
}

// ---- prep: convert+transpose weights into d_ws ----
// w1t: [128 cols][224 k] bf16 (k>=208 zero)   w2t: [64 cols][128 k] bf16
__global__ void prep_weights(const float* __restrict__ W1f, const float* __restrict__ W2f,
                             short* __restrict__ w1t, short* __restrict__ w2t) {
    int i = blockIdx.x * blockDim.x + threadIdx.x;
    if (i < H1DIM * KPAD) {
        int c = i / KPAD, k = i % KPAD;
        w1t[i] = f2bf(k < INDIM ? W1f[k * H1DIM + c] : 0.f);
    } else {
        int t = i - H1DIM * KPAD;
        if (t < H2DIM * H1DIM) {
            int c = t / H1DIM, k = t % H1DIM;
            w2t[t] = f2bf(W2f[k * H2DIM + c]);
        }
    }
}

__global__ __launch_bounds__(THREADS, 4)   // target: 4 blocks/CU, 16 waves/CU
void stage_policy_mlp(const float* __restrict__ x,
                      const float* __restrict__ h_node,
                      const float* __restrict__ h_dag,
                      const float* __restrict__ h_glob,
                      const float* __restrict__ b1,
                      const float* __restrict__ b2,
                      const float* __restrict__ W3,
                      const float* __restrict__ b3,
                      const int*   __restrict__ stage_idx,
                      const int*   __restrict__ batch,
                      const int*   __restrict__ nsa,
                      const short* __restrict__ w1t,
                      const short* __restrict__ w2t,
                      float*       __restrict__ out,
                      int M)
{
    __shared__ short Asm[ROWS * AS];            // 29,696 B; reused as h1 [64][H1S]
    __shared__ int rIdx[ROWS], rBm[ROWS], rG[ROWS];

    const int tid  = threadIdx.x;
    const int lane = tid & 63;
    const int w    = tid >> 6;       // wave 0..3
    const int l15  = lane & 15;
    const int lh   = lane >> 4;      // 0..3
    const int m0   = blockIdx.x * ROWS;
    const int wr   = w & 1;          // row half: rows 32*wr .. +31
    const int wc   = w >> 1;         // col half: cols 64*wc .. +63

    // ---- per-row metadata (wave 0 only) ----
    if (tid < ROWS) {
        int m = m0 + tid; if (m >= M) m = M - 1;
        int idx = stage_idx[m];
        rIdx[tid] = idx;
        rBm[tid]  = batch[idx];
        int g = 0, cum = 0;
        #pragma unroll
        for (int i = 0; i < 16; ++i) { cum += nsa[i]; if (m >= cum) g = i + 1; }
        rG[tid] = g > 15 ? 15 : g;
    }
    __syncthreads();

    // ---- gather A-tile as bf16 [64 rows][AS], k-major ----
    if (tid < 128) {                                   // x: 16 f/row
        int r = tid >> 1, q = tid & 1;
        stage8(&Asm[r * AS + q * 8], x + (size_t)rIdx[r] * 16 + q * 8);
    }
    for (int u = tid; u < 512; u += THREADS) {         // h_node
        int r = u >> 3, q = u & 7;
        stage8(&Asm[r * AS + 16 + q * 8], h_node + (size_t)rIdx[r] * 64 + q * 8);
    }
    for (int u = tid; u < 512; u += THREADS) {         // h_dag[batch]
        int r = u >> 3, q = u & 7;
        stage8(&Asm[r * AS + 80 + q * 8], h_dag + (size_t)rBm[r] * 64 + q * 8);
    }
    for (int u = tid; u < 512; u += THREADS) {         // h_glob[g]
        int r = u >> 3, q = u & 7;
        stage8(&Asm[r * AS + 144 + q * 8], h_glob + (size_t)rG[r] * 64 + q * 8);
    }
    if (tid < 128) {                                   // zero pad k 208..223
        int r = tid >> 1, q = tid & 1;
        short8 z = {0,0,0,0,0,0,0,0};
        *(short8*)&Asm[r * AS + 208 + q * 8] = z;
    }
    __syncthreads();

    // ---- layer 1: [64x224] @ [224x128]; wave = 2 row-tiles x 4 col-tiles ----
    // B-fragments: distance-1 prefetch inside the k-loop (8 live frags = 32 VGPRs,
    // fits the 128-VGPR budget; exposed L2 latency is covered by 16 waves/CU TLP).
    f32x4 acc1[2][4];
    #pragma unroll
    for (int i = 0; i < 2; ++i)
        #pragma unroll
        for (int j = 0; j < 4; ++j) { f32x4 z = {0.f,0.f,0.f,0.f}; acc1[i][j] = z; }

    const short* wbase = w1t + ((wc * 4) * 16 + l15) * KPAD + lh * 8;  // col-tile 0 of this wave
    short8 bcur[4], bnxt[4];
    #pragma unroll
    for (int j = 0; j < 4; ++j)
        bcur[j] = *(const short8*)(wbase + j * 16 * KPAD);

    #pragma unroll
    for (int k = 0; k < 7; ++k) {
        if (k < 6) {
            #pragma unroll
            for (int j = 0; j < 4; ++j)
                bnxt[j] = *(const short8*)(wbase + j * 16 * KPAD + (k + 1) * 32);
        }
        short8 a0 = *(const short8*)&Asm[(wr * 32      + l15) * AS + k * 32 + lh * 8];
        short8 a1 = *(const short8*)&Asm[(wr * 32 + 16 + l15) * AS + k * 32 + lh * 8];
        #pragma unroll
        for (int j = 0; j < 4; ++j) {
            acc1[0][j] = __builtin_amdgcn_mfma_f32_16x16x32_bf16(a0, bcur[j], acc1[0][j], 0, 0, 0);
            acc1[1][j] = __builtin_amdgcn_mfma_f32_16x16x32_bf16(a1, bcur[j], acc1[1][j], 0, 0, 0);
        }
        #pragma unroll
        for (int j = 0; j < 4; ++j) bcur[j] = bnxt[j];  // renamed away by full unroll
    }
    __syncthreads();   // all A-tile reads done before overwriting region with h1

    // ---- epilogue L1: bias + relu -> bf16 h1 [64][H1S] (C-layout: col=l15, row=4*lh+p) ----
    short* h1s = Asm;
    #pragma unroll
    for (int i = 0; i < 2; ++i)
        #pragma unroll
        for (int j = 0; j < 4; ++j) {
            int c = (wc * 4 + j) * 16 + l15;
            float bias = b1[c];
            #pragma unroll
            for (int p = 0; p < 4; ++p) {
                int row = wr * 32 + i * 16 + lh * 4 + p;
                h1s[row * H1S + c] = f2bf(fmaxf(acc1[i][j][p] + bias, 0.f));
            }
        }
    __syncthreads();

    // ---- layer 2: [64x128] @ [128x64]; wave = rows 16w.. x 4 col-tiles ----
    // W2 fragments: distance-1 prefetch, 8 live frags max.
    f32x4 acc2[4];
    #pragma unroll
    for (int j = 0; j < 4; ++j) { f32x4 z = {0.f,0.f,0.f,0.f}; acc2[j] = z; }

    const short* w2base = w2t + l15 * H1DIM + lh * 8;
    short8 c2cur[4], c2nxt[4];
    #pragma unroll
    for (int j = 0; j < 4; ++j)
        c2cur[j] = *(const short8*)(w2base + j * 16 * H1DIM);

    #pragma unroll
    for (int k = 0; k < 4; ++k) {
        if (k < 3) {
            #pragma unroll
            for (int j = 0; j < 4; ++j)
                c2nxt[j] = *(const short8*)(w2base + j * 16 * H1DIM + (k + 1) * 32);
        }
        short8 a2 = *(const short8*)&h1s[(w * 16 + l15) * H1S + k * 32 + lh * 8];
        #pragma unroll
        for (int j = 0; j < 4; ++j)
            acc2[j] = __builtin_amdgcn_mfma_f32_16x16x32_bf16(a2, c2cur[j], acc2[j], 0, 0, 0);
        #pragma unroll
        for (int j = 0; j < 4; ++j) c2cur[j] = c2nxt[j];
    }

    // ---- layer 3: relu(h2)·W3, reduce over 64 cols (4 tiles in-lane + 16-lane shfl) ----
    float part[4] = {0.f, 0.f, 0.f, 0.f};
    #pragma unroll
    for (int j = 0; j < 4; ++j) {
        int c = j * 16 + l15;
        float bb = b2[c], w3 = W3[c];
        #pragma unroll
        for (int p = 0; p < 4; ++p)
            part[p] += fmaxf(acc2[j][p] + bb, 0.f) * w3;
    }
    #pragma unroll
    for (int s = 8; s >= 1; s >>= 1) {
        #pragma unroll
        for (int p = 0; p < 4; ++p) part[p] += __shfl_xor(part[p], s);
    }
    if (l15 == 0) {
        float bias3 = b3[0];
        #pragma unroll
        for (int p = 0; p < 4; ++p) {
            int m = m0 + w * 16 + lh * 4 + p;
            if (m < M) out[m] = part[p] + bias3;
        }
    }
}

extern "C" void kernel_launch(void* const* d_in, const int* in_sizes, int n_in,
                              void* d_out, int out_size, void* d_ws, size_t ws_size,
                              hipStream_t stream) {
    const float* x       = (const float*)d_in[0];
    const float* h_node  = (const float*)d_in[1];
    const float* h_dag   = (const float*)d_in[2];
    const float* h_glob  = (const float*)d_in[3];
    const float* W1      = (const float*)d_in[4];
    const float* b1      = (const float*)d_in[5];
    const float* W2      = (const float*)d_in[6];
    const float* b2      = (const float*)d_in[7];
    const float* W3      = (const float*)d_in[8];
    const float* b3      = (const float*)d_in[9];
    const int* stage_idx = (const int*)d_in[10];
    const int* batch     = (const int*)d_in[11];
    const int* nsa       = (const int*)d_in[12];
    float* out           = (float*)d_out;

    const int M = in_sizes[10];

    short* w1t = (short*)d_ws;                    // 128*224 bf16 = 57,344 B
    short* w2t = w1t + H1DIM * KPAD;              // 64*128  bf16 = 16,384 B

    const int prep_elems = H1DIM * KPAD + H2DIM * H1DIM;   // 36,864
    hipLaunchKernelGGL(prep_weights, dim3((prep_elems + THREADS - 1) / THREADS),
                       dim3(THREADS), 0, stream, W1, W2, w1t, w2t);

    const int grid = (M + ROWS - 1) / ROWS;
    hipLaunchKernelGGL(stage_policy_mlp, dim3(grid), dim3(THREADS), 0, stream,
                       x, h_node, h_dag, h_glob, b1, b2, W3, b3,
                       stage_idx, batch, nsa, w1t, w2t, out, M);
}